// Round 1
// baseline (154.105 us; speedup 1.0000x reference)
//
#include <hip/hip_runtime.h>
#include <cmath>

#define NBATCH 8
#define NGT    64
#define NPR    32768
#define NC     80

// -------- Phase 1: per-(b,g) argmax over P of masked IoU (numpy tie-break:
// first index of the max wins) --------
__global__ __launch_bounds__(256) void k_bestp(const float* __restrict__ gt,
                                               const float* __restrict__ pr,
                                               int* __restrict__ bestp) {
#pragma clang fp contract(off)
    const int bg  = blockIdx.x;            // b*NGT + g
    const int tid = threadIdx.x;
    const float* g6 = gt + (size_t)bg * 6;
    const float gcx = g6[0], gcy = g6[1], gw = g6[2], gh = g6[3];
    const bool  valid = (gcx != -1.0f);
    const float gy1 = gcy - gh * 0.5f;
    const float gx1 = gcx - gw * 0.5f;
    const float gy2 = gcy + gh * 0.5f;
    const float gx2 = gcx + gw * 0.5f;
    const float ga  = gw * gh;

    float best = -1.0f;   // every iou >= 0, so first candidate always wins
    int   bidx = 0;
    for (int p = tid; p < NPR; p += 256) {
        float4 pv = ((const float4*)pr)[p];
        float py1 = pv.y - pv.w * 0.5f;
        float px1 = pv.x - pv.z * 0.5f;
        float py2 = pv.y + pv.w * 0.5f;
        float px2 = pv.x + pv.z * 0.5f;
        float pa  = pv.z * pv.w;
        float ih  = fmaxf(0.0f, fminf(gy2, py2) - fmaxf(gy1, py1));
        float iw  = fmaxf(0.0f, fminf(gx2, px2) - fmaxf(gx1, px1));
        float inter = iw * ih;
        float uni   = ga + pa - inter;
        float iou   = inter / (uni + 1e-5f);
        iou = valid ? iou : 0.0f;
        if (iou > best) { best = iou; bidx = p; }   // ascending p: first max kept
    }

    __shared__ float rv[256];
    __shared__ int   ri[256];
    rv[tid] = best; ri[tid] = bidx;
    __syncthreads();
    for (int s = 128; s > 0; s >>= 1) {
        if (tid < s) {
            float v2 = rv[tid + s]; int i2 = ri[tid + s];
            if (v2 > rv[tid] || (v2 == rv[tid] && i2 < ri[tid])) {
                rv[tid] = v2; ri[tid] = i2;
            }
        }
        __syncthreads();
    }
    if (tid == 0) bestp[bg] = ri[0];
}

// -------- Phase 2: per-(b,p) assignment + regression targets + one-hot --------
__global__ __launch_bounds__(256) void k_assign(const float* __restrict__ gt,
                                                const float* __restrict__ pr,
                                                const int* __restrict__ bestp,
                                                float* __restrict__ out_cls,
                                                float* __restrict__ out_loc,
                                                float* __restrict__ out_msk) {
#pragma clang fp contract(off)
    const int b   = blockIdx.y;
    const int tid = threadIdx.x;
    const int p   = blockIdx.x * 256 + tid;

    __shared__ float s_cx[NGT], s_cy[NGT], s_y1[NGT], s_x1[NGT], s_y2[NGT], s_x2[NGT];
    __shared__ float s_ga[NGT], s_lw[NGT], s_lh[NGT], s_lab[NGT], s_conf[NGT];
    __shared__ int   s_bp[NGT], s_val[NGT];
    __shared__ int   s_cls[256];

    if (tid < NGT) {
        const float* g6 = gt + ((size_t)b * NGT + tid) * 6;
        float cx = g6[0], cy = g6[1], w = g6[2], h = g6[3];
        s_cx[tid] = cx; s_cy[tid] = cy;
        s_y1[tid] = cy - h * 0.5f;
        s_x1[tid] = cx - w * 0.5f;
        s_y2[tid] = cy + h * 0.5f;
        s_x2[tid] = cx + w * 0.5f;
        s_ga[tid] = w * h;
        s_lw[tid] = (w > 0.0f) ? logf(fmaxf(w, 1e-20f)) : 0.0f;
        s_lh[tid] = (h > 0.0f) ? logf(fmaxf(h, 1e-20f)) : 0.0f;
        s_lab[tid]  = g6[4];
        s_conf[tid] = g6[5];
        s_val[tid]  = (cx != -1.0f) ? 1 : 0;
        s_bp[tid]   = bestp[b * NGT + tid];
    }
    __syncthreads();

    float4 pv = ((const float4*)pr)[p];
    const float px = pv.x, py = pv.y, pw = pv.z, ph = pv.w;
    const float py1 = py - ph * 0.5f;
    const float px1 = px - pw * 0.5f;
    const float py2 = py + ph * 0.5f;
    const float px2 = px + pw * 0.5f;
    const float pa  = pw * ph;

    int  g_th = -1, g_bs = -1;
    bool ignore = false;
    float W = 0.0f, Scx = 0.0f, Scy = 0.0f, Slw = 0.0f, Slh = 0.0f;

    for (int g = 0; g < NGT; ++g) {
        float ih = fmaxf(0.0f, fminf(s_y2[g], py2) - fmaxf(s_y1[g], py1));
        float iw = fmaxf(0.0f, fminf(s_x2[g], px2) - fmaxf(s_x1[g], px1));
        float inter = iw * ih;
        float uni   = s_ga[g] + pa - inter;
        float iou   = inter / (uni + 1e-5f);
        iou = s_val[g] ? iou : 0.0f;
        bool th = (iou >= 0.5f);
        bool bs = (s_bp[g] == p) && (s_conf[g] > 0.0f);
        if (th) g_th = g;               // max over g of (th ? g : -1)
        if (bs) g_bs = g;
        ignore = ignore || (iou < 0.5f && iou >= 0.4f);
        float wg = (float)th + (float)bs;
        W   += wg;
        Scx += wg * s_cx[g];
        Scy += wg * s_cy[g];
        Slw += wg * s_lw[g];
        Slh += wg * s_lh[g];
    }

    const int  win     = (g_bs >= 0) ? g_bs : g_th;
    const bool matched = (win >= 0);
    const int  cls     = matched ? (int)s_lab[win] : NC;
    float msk = matched ? 0.0f : 1.0f;
    if (ignore) msk = -1.0f;

    const float hcx = (Scx - W * px) / pw;
    const float hcy = (Scy - W * py) / ph;
    const float hw  = Slw - W * logf(pw);
    const float hh  = Slh - W * logf(ph);

    const size_t bp_i = (size_t)b * NPR + p;
    ((float4*)out_loc)[bp_i] = make_float4(hcx, hcy, hw, hh);
    out_msk[bp_i] = msk;

    // Cooperative coalesced one-hot tile write: 256 anchors x 80 classes.
    s_cls[tid] = cls;
    __syncthreads();
    const size_t base4 = ((size_t)b * NPR + (size_t)blockIdx.x * 256) * NC / 4;
    float4* oc4 = (float4*)out_cls;
    #pragma unroll
    for (int k = 0; k < (256 * NC / 4) / 256; ++k) {   // 20 iterations
        int idx = tid + k * 256;          // float4 index within the tile
        int e0  = idx * 4;                // element index; NC % 4 == 0 so all 4
        int pl  = e0 / NC;                // lanes of this float4 share one anchor
        int c0  = e0 - pl * NC;
        int cl  = s_cls[pl];
        float4 v;
        v.x = (c0     == cl) ? 1.0f : 0.0f;
        v.y = (c0 + 1 == cl) ? 1.0f : 0.0f;
        v.z = (c0 + 2 == cl) ? 1.0f : 0.0f;
        v.w = (c0 + 3 == cl) ? 1.0f : 0.0f;
        oc4[base4 + idx] = v;
    }
}

extern "C" void kernel_launch(void* const* d_in, const int* in_sizes, int n_in,
                              void* d_out, int out_size, void* d_ws, size_t ws_size,
                              hipStream_t stream) {
    const float* gt = (const float*)d_in[0];
    const float* pr = (const float*)d_in[1];   // reference uses pr_boxes[0] only
    int* bestp = (int*)d_ws;                   // NBATCH*NGT ints

    float* out_cls = (float*)d_out;                              // B*P*80
    float* out_loc = out_cls + (size_t)NBATCH * NPR * NC;        // B*P*4
    float* out_msk = out_loc + (size_t)NBATCH * NPR * 4;         // B*P

    k_bestp<<<NBATCH * NGT, 256, 0, stream>>>(gt, pr, bestp);
    dim3 g2(NPR / 256, NBATCH);
    k_assign<<<g2, 256, 0, stream>>>(gt, pr, bestp, out_cls, out_loc, out_msk);
}

// Round 2
// 134.065 us; speedup vs baseline: 1.1495x; 1.1495x over previous
//
#include <hip/hip_runtime.h>
#include <cmath>

#define NBATCH 8
#define NGT    64
#define NPR    32768
#define NC     80

#define CHUNKS 16
#define CHUNK  (NPR / CHUNKS)   // 2048 anchors per chunk
#define GTPB   8                // gt boxes per block

// -------- Phase 1: per-(b,g) partial argmax over one anchor chunk.
// Each block: 8 gt boxes x 2048 anchors. numpy tie-break (first index of the
// max wins) preserved: thread-level ascending-p strict '>', lane/wave levels
// compare (val, idx) explicitly, lower idx wins on equal val. --------
__global__ __launch_bounds__(256) void k_bestp_part(const float* __restrict__ gt,
                                                    const float* __restrict__ pr,
                                                    float* __restrict__ pval,
                                                    int* __restrict__ pidx) {
#pragma clang fp contract(off)
    const int chunk = blockIdx.x;    // 0..15
    const int gg    = blockIdx.y;    // 0..63  (bg group of 8)
    const int tid   = threadIdx.x;

    __shared__ float sy1[GTPB], sx1[GTPB], sy2[GTPB], sx2[GTPB], sga[GTPB];
    __shared__ int   sv[GTPB];
    if (tid < GTPB) {
        const float* g6 = gt + ((size_t)gg * GTPB + tid) * 6;
        float cx = g6[0], cy = g6[1], w = g6[2], h = g6[3];
        sy1[tid] = cy - h * 0.5f;
        sx1[tid] = cx - w * 0.5f;
        sy2[tid] = cy + h * 0.5f;
        sx2[tid] = cx + w * 0.5f;
        sga[tid] = w * h;
        sv[tid]  = (cx != -1.0f) ? 1 : 0;
    }
    __syncthreads();

    float gy1[GTPB], gx1[GTPB], gy2[GTPB], gx2[GTPB], ga[GTPB];
    int   gv[GTPB];
    #pragma unroll
    for (int j = 0; j < GTPB; ++j) {
        gy1[j] = sy1[j]; gx1[j] = sx1[j]; gy2[j] = sy2[j]; gx2[j] = sx2[j];
        ga[j] = sga[j]; gv[j] = sv[j];
    }

    float best[GTPB]; int bi[GTPB];
    #pragma unroll
    for (int j = 0; j < GTPB; ++j) { best[j] = -1.0f; bi[j] = 0; }

    const int base = chunk * CHUNK;
    #pragma unroll 4
    for (int k = 0; k < CHUNK / 256; ++k) {          // 8 iterations
        int p = base + k * 256 + tid;                // ascending p per thread
        float4 pv = ((const float4*)pr)[p];
        float py1 = pv.y - pv.w * 0.5f;
        float px1 = pv.x - pv.z * 0.5f;
        float py2 = pv.y + pv.w * 0.5f;
        float px2 = pv.x + pv.z * 0.5f;
        float pa  = pv.z * pv.w;
        #pragma unroll
        for (int j = 0; j < GTPB; ++j) {
            float ih = fmaxf(0.0f, fminf(gy2[j], py2) - fmaxf(gy1[j], py1));
            float iw = fmaxf(0.0f, fminf(gx2[j], px2) - fmaxf(gx1[j], px1));
            float inter = iw * ih;
            float uni   = ga[j] + pa - inter;
            float iou   = inter / (uni + 1e-5f);
            iou = gv[j] ? iou : 0.0f;
            if (iou > best[j]) { best[j] = iou; bi[j] = p; }
        }
    }

    // 64-lane shuffle argmax per gt (lower idx wins ties)
    #pragma unroll
    for (int j = 0; j < GTPB; ++j) {
        #pragma unroll
        for (int off = 32; off > 0; off >>= 1) {
            float ov = __shfl_down(best[j], off);
            int   oi = __shfl_down(bi[j], off);
            if (ov > best[j] || (ov == best[j] && oi < bi[j])) {
                best[j] = ov; bi[j] = oi;
            }
        }
    }

    __shared__ float rv[4][GTPB];
    __shared__ int   rix[4][GTPB];
    const int wave = tid >> 6;
    if ((tid & 63) == 0) {
        #pragma unroll
        for (int j = 0; j < GTPB; ++j) { rv[wave][j] = best[j]; rix[wave][j] = bi[j]; }
    }
    __syncthreads();
    if (tid < GTPB) {
        float v = rv[0][tid]; int i = rix[0][tid];
        #pragma unroll
        for (int w = 1; w < 4; ++w) {
            float v2 = rv[w][tid]; int i2 = rix[w][tid];
            if (v2 > v || (v2 == v && i2 < i)) { v = v2; i = i2; }
        }
        int bg = gg * GTPB + tid;
        pval[bg * CHUNKS + chunk] = v;
        pidx[bg * CHUNKS + chunk] = i;
    }
}

// -------- Phase 2: per-(b,p) assignment + regression targets + one-hot.
// Combines the chunk partials into bestp in the preamble (fused reduce). ----
__global__ __launch_bounds__(256) void k_assign(const float* __restrict__ gt,
                                                const float* __restrict__ pr,
                                                const float* __restrict__ pval,
                                                const int* __restrict__ pidx,
                                                float* __restrict__ out_cls,
                                                float* __restrict__ out_loc,
                                                float* __restrict__ out_msk) {
#pragma clang fp contract(off)
    const int b   = blockIdx.y;
    const int tid = threadIdx.x;
    const int p   = blockIdx.x * 256 + tid;

    __shared__ float s_cx[NGT], s_cy[NGT], s_y1[NGT], s_x1[NGT], s_y2[NGT], s_x2[NGT];
    __shared__ float s_ga[NGT], s_lw[NGT], s_lh[NGT], s_lab[NGT], s_conf[NGT];
    __shared__ int   s_bp[NGT], s_val[NGT];
    __shared__ int   s_cls[256];

    if (tid < NGT) {
        const float* g6 = gt + ((size_t)b * NGT + tid) * 6;
        float cx = g6[0], cy = g6[1], w = g6[2], h = g6[3];
        s_cx[tid] = cx; s_cy[tid] = cy;
        s_y1[tid] = cy - h * 0.5f;
        s_x1[tid] = cx - w * 0.5f;
        s_y2[tid] = cy + h * 0.5f;
        s_x2[tid] = cx + w * 0.5f;
        s_ga[tid] = w * h;
        s_lw[tid] = (w > 0.0f) ? logf(fmaxf(w, 1e-20f)) : 0.0f;
        s_lh[tid] = (h > 0.0f) ? logf(fmaxf(h, 1e-20f)) : 0.0f;
        s_lab[tid]  = g6[4];
        s_conf[tid] = g6[5];
        s_val[tid]  = (cx != -1.0f) ? 1 : 0;
        // combine chunk partials -> bestp (ascending chunk, lower idx on tie)
        int bg = b * NGT + tid;
        float v = pval[bg * CHUNKS + 0]; int i = pidx[bg * CHUNKS + 0];
        #pragma unroll
        for (int c = 1; c < CHUNKS; ++c) {
            float v2 = pval[bg * CHUNKS + c]; int i2 = pidx[bg * CHUNKS + c];
            if (v2 > v || (v2 == v && i2 < i)) { v = v2; i = i2; }
        }
        s_bp[tid] = i;
    }
    __syncthreads();

    float4 pv = ((const float4*)pr)[p];
    const float px = pv.x, py = pv.y, pw = pv.z, ph = pv.w;
    const float py1 = py - ph * 0.5f;
    const float px1 = px - pw * 0.5f;
    const float py2 = py + ph * 0.5f;
    const float px2 = px + pw * 0.5f;
    const float pa  = pw * ph;

    int  g_th = -1, g_bs = -1;
    bool ignore = false;
    float W = 0.0f, Scx = 0.0f, Scy = 0.0f, Slw = 0.0f, Slh = 0.0f;

    for (int g = 0; g < NGT; ++g) {
        float ih = fmaxf(0.0f, fminf(s_y2[g], py2) - fmaxf(s_y1[g], py1));
        float iw = fmaxf(0.0f, fminf(s_x2[g], px2) - fmaxf(s_x1[g], px1));
        float inter = iw * ih;
        float uni   = s_ga[g] + pa - inter;
        float iou   = inter / (uni + 1e-5f);
        iou = s_val[g] ? iou : 0.0f;
        bool th = (iou >= 0.5f);
        bool bs = (s_bp[g] == p) && (s_conf[g] > 0.0f);
        if (th) g_th = g;
        if (bs) g_bs = g;
        ignore = ignore || (iou < 0.5f && iou >= 0.4f);
        float wg = (float)th + (float)bs;
        W   += wg;
        Scx += wg * s_cx[g];
        Scy += wg * s_cy[g];
        Slw += wg * s_lw[g];
        Slh += wg * s_lh[g];
    }

    const int  win     = (g_bs >= 0) ? g_bs : g_th;
    const bool matched = (win >= 0);
    const int  cls     = matched ? (int)s_lab[win] : NC;
    float msk = matched ? 0.0f : 1.0f;
    if (ignore) msk = -1.0f;

    const float hcx = (Scx - W * px) / pw;
    const float hcy = (Scy - W * py) / ph;
    const float hw  = Slw - W * logf(pw);
    const float hh  = Slh - W * logf(ph);

    const size_t bp_i = (size_t)b * NPR + p;
    ((float4*)out_loc)[bp_i] = make_float4(hcx, hcy, hw, hh);
    out_msk[bp_i] = msk;

    // Cooperative coalesced one-hot tile write: 256 anchors x 80 classes.
    s_cls[tid] = cls;
    __syncthreads();
    const size_t base4 = ((size_t)b * NPR + (size_t)blockIdx.x * 256) * NC / 4;
    float4* oc4 = (float4*)out_cls;
    #pragma unroll
    for (int k = 0; k < (256 * NC / 4) / 256; ++k) {   // 20 iterations
        int idx = tid + k * 256;
        int e0  = idx * 4;
        int pl  = e0 / NC;
        int c0  = e0 - pl * NC;
        int cl  = s_cls[pl];
        float4 v;
        v.x = (c0     == cl) ? 1.0f : 0.0f;
        v.y = (c0 + 1 == cl) ? 1.0f : 0.0f;
        v.z = (c0 + 2 == cl) ? 1.0f : 0.0f;
        v.w = (c0 + 3 == cl) ? 1.0f : 0.0f;
        oc4[base4 + idx] = v;
    }
}

extern "C" void kernel_launch(void* const* d_in, const int* in_sizes, int n_in,
                              void* d_out, int out_size, void* d_ws, size_t ws_size,
                              hipStream_t stream) {
    const float* gt = (const float*)d_in[0];
    const float* pr = (const float*)d_in[1];   // reference uses pr_boxes[0] only

    float* pval = (float*)d_ws;                             // 512*16 floats
    int*   pidx = (int*)((char*)d_ws + NBATCH * NGT * CHUNKS * sizeof(float));

    float* out_cls = (float*)d_out;                         // B*P*80
    float* out_loc = out_cls + (size_t)NBATCH * NPR * NC;   // B*P*4
    float* out_msk = out_loc + (size_t)NBATCH * NPR * 4;    // B*P

    dim3 g1(CHUNKS, NBATCH * NGT / GTPB);   // 16 x 64 = 1024 blocks
    k_bestp_part<<<g1, 256, 0, stream>>>(gt, pr, pval, pidx);

    dim3 g2(NPR / 256, NBATCH);             // 128 x 8 = 1024 blocks
    k_assign<<<g2, 256, 0, stream>>>(gt, pr, pval, pidx, out_cls, out_loc, out_msk);
}